// Round 10
// baseline (556.817 us; speedup 1.0000x reference)
//
#include <hip/hip_runtime.h>
#include <hip/hip_fp16.h>
#include <math.h>

// ---------------------------------------------------------------------------
// TensorFieldNetwork on MI355X — round 10.
// Round-9 model: pair loops are pure VALU-instruction bound (~48 two-cycle
// instr per pair-channel; VALUBusy ~76% invariant to occupancy). Lever:
// packed dual-fp32 (v_pk_fma_f32). Each thread now owns a CHANNEL PAIR
// (2f,2f+1) with float2 ext-vector math: 21 accum fmas -> 21 pk ops for 2
// channels; table re-packed per channel-pair ({v2h,d2h} -> 1 load + hfma2 +
// 2 cvt per filter per 2ch); x stored f32 [N][4][C] (8B loads, no cvts).
// Static count ~26 instr/channel vs 48 -> ~1.8x on pair loops.
// ---------------------------------------------------------------------------

typedef float v2f __attribute__((ext_vector_type(2)));

constexpr int   N_     = 768;
constexpr int   C_     = 128;
constexpr int   FP_    = C_ / 2;        // 64 channel pairs
constexpr int   M_     = 512;
constexpr int   NSPLIT = 3;
constexpr int   NB_    = N_ / NSPLIT;   // 256 neighbors per pair-block
constexpr int   TA_    = 3;             // atoms per finish block
constexpr float DMAX_  = 6.4f;
constexpr float GAMMA_ = 1.6f;          // RBF / (HIGH - LOW)

__device__ inline v2f vfma(v2f a, v2f b, v2f c) { return __builtin_elementwise_fma(a, b, c); }
__device__ inline v2f sp(float x) { return (v2f){x, x}; }
__device__ inline __half2 H2(unsigned u) { __half2 h; *(unsigned*)&h = u; return h; }
__device__ inline v2f h2v(__half2 h) {
    return (v2f){__half2float(__low2half(h)), __half2float(__high2half(h))};
}

// ---------------------------------------------------------------------------
// Kernel A: build radial tables packed per channel-pair.
// tab[(m*12 + i)*FP + fp] = uint2{ half2{v[2fp],v[2fp+1]}, half2{d...} }.
// 256 thr: fp = tid&63, g = tid>>6 handles filters g*3..g*3+2.
// ---------------------------------------------------------------------------
__global__ __launch_bounds__(256) void build_table_kernel(
    const float* __restrict__ Rw1, const float* __restrict__ Rb1,
    const float* __restrict__ Rw2, const float* __restrict__ Rb2,
    uint2* __restrict__ tab, float delta)
{
    const int fp = threadIdx.x & 63, g = threadIdx.x >> 6;
    const int c0 = fp * 2;
    const int m0 = blockIdx.x * 4;

    __shared__ float hs[4][5][C_];

    float rbf[5][4];
    const float cent[4] = {0.0f, 2.5f / 3.0f, 5.0f / 3.0f, 2.5f};
#pragma unroll
    for (int mm = 0; mm < 5; ++mm) {
        int m = m0 + mm; if (m > M_ - 1) m = M_ - 1;
        const float d = (float)m * delta;
#pragma unroll
        for (int k = 0; k < 4; ++k) {
            const float t = d - cent[k];
            rbf[mm][k] = expf(-GAMMA_ * t * t);
        }
    }

    for (int ii = 0; ii < 3; ++ii) {
        const int i = g * 3 + ii;
        v2f w1v[4];
#pragma unroll
        for (int k = 0; k < 4; ++k)
            w1v[k] = *(const v2f*)&Rw1[(i * 4 + k) * C_ + c0];
        const v2f b1v = *(const v2f*)&Rb1[i * C_ + c0];

        __syncthreads();               // previous filter's readers done
#pragma unroll
        for (int mm = 0; mm < 5; ++mm) {
            v2f acc = b1v;
#pragma unroll
            for (int k = 0; k < 4; ++k) acc = vfma(sp(rbf[mm][k]), w1v[k], acc);
            acc.x = fmaxf(acc.x, 0.0f);
            acc.y = fmaxf(acc.y, 0.0f);
            *(v2f*)&hs[g][mm][c0] = acc;
        }
        __syncthreads();

        const v2f b2v = *(const v2f*)&Rb2[i * C_ + c0];
        v2f out[5] = {b2v, b2v, b2v, b2v, b2v};
        for (int c = 0; c < C_; ++c) {
            const v2f w = *(const v2f*)&Rw2[((size_t)i * C_ + c) * C_ + c0];
#pragma unroll
            for (int mm = 0; mm < 5; ++mm) out[mm] = vfma(sp(hs[g][mm][c]), w, out[mm]);
        }
#pragma unroll
        for (int mm = 0; mm < 4; ++mm) {
            const int m = m0 + mm;
            if (m < M_) {
                const v2f dl = out[mm + 1] - out[mm];
                const __half2 vh = __floats2half2_rn(out[mm].x, out[mm].y);
                const __half2 dh = __floats2half2_rn(dl.x, dl.y);
                tab[((size_t)m * 12 + i) * FP_ + fp] =
                    make_uint2(*(const unsigned*)&vh, *(const unsigned*)&dh);
            }
        }
    }
}

// ---------------------------------------------------------------------------
// Kernel B: embedding  e[b,f] (f32 [N][C])
// ---------------------------------------------------------------------------
__global__ __launch_bounds__(256) void embed_kernel(
    const float* __restrict__ onehot, const float* __restrict__ eW,
    const float* __restrict__ eb, float* __restrict__ e)
{
    const int idx = blockIdx.x * 256 + threadIdx.x;
    const int b = idx >> 7, f = idx & 127;
    float acc = eb[f];
#pragma unroll
    for (int t = 0; t < 8; ++t) acc = fmaf(onehot[b * 8 + t], eW[f * 8 + t], acc);
    e[idx] = acc;
}

// ---------------------------------------------------------------------------
// Pair setup: {u, fr} + table record offset (q*12+RI)*FP for NB_ neighbors.
// ---------------------------------------------------------------------------
__device__ inline void pair_setup(const float* __restrict__ r, int a, int bbase,
                                  int tid, int RI, float4* pair, int* qoff)
{
    const float rax = r[a * 3 + 0], ray = r[a * 3 + 1], raz = r[a * 3 + 2];
    for (int i = tid; i < NB_; i += 256) {
        const int b = bbase + i;
        const float dx = rax - r[b * 3 + 0];
        const float dy = ray - r[b * 3 + 1];
        const float dz = raz - r[b * 3 + 2];
        const float d2 = fmaf(dx, dx, fmaf(dy, dy, dz * dz));
        const float d  = sqrtf(fmaxf(d2, 1e-12f));
        const float inv = 1.0f / (d + 1e-8f);
        const float t = d * ((float)(M_ - 1) / DMAX_);
        int q = (int)t; q = q > M_ - 2 ? M_ - 2 : q;
        const float fr = fminf(t - (float)q, 1.0f);
        pair[i] = make_float4(dx * inv, dy * inv, dz * inv, fr);
        qoff[i] = (q * 12 + RI) * FP_;
    }
}

// ---------------------------------------------------------------------------
// Kernel C1: layer-0 pair phase. grid = NSPLIT*N x 256 thr.
// thread = (part = tid>>6) x (fp = tid&63); 64 iters per part.
// ---------------------------------------------------------------------------
__global__ __launch_bounds__(256, 8) void pair0_kernel(
    const float* __restrict__ r, const float* __restrict__ e,
    const uint2* __restrict__ tab, float* __restrict__ P)
{
    const int a = blockIdx.x / NSPLIT, p = blockIdx.x - a * NSPLIT;
    const int tid = threadIdx.x;
    const int fp = tid & 63, part = tid >> 6;
    const int bbase = p * NB_;

    __shared__ float4 pair[NB_];
    __shared__ int    qoff[NB_];
    __shared__ float  sred[4][4][C_];

    pair_setup(r, a, bbase, tid, 0, pair, qoff);
    __syncthreads();

    v2f c00 = sp(0.f), cx = sp(0.f), cy = sp(0.f), cz = sp(0.f);
    const uint2* tb = tab + fp;
    const float* ef = e + (size_t)bbase * C_ + 2 * fp;
    const int iBeg = part * (NB_ / 4), iEnd = iBeg + (NB_ / 4);
#pragma unroll 2
    for (int i = iBeg; i < iEnd; ++i) {
        const float4 pr = pair[i];
        const uint2* tp = tb + qoff[i];
        const uint2 w0 = tp[0 * FP_], w1 = tp[1 * FP_];
        const v2f e2 = *(const v2f*)&ef[(size_t)i * C_];
        const __half2 fr2 = __float2half2_rn(pr.w);
        const v2f t0 = h2v(__hfma2(fr2, H2(w0.y), H2(w0.x)));
        const v2f t1 = h2v(__hfma2(fr2, H2(w1.y), H2(w1.x)));
        c00 = vfma(t0, e2, c00);
        const v2f te = t1 * e2;
        cx = vfma(te, sp(pr.x), cx);
        cy = vfma(te, sp(pr.y), cy);
        cz = vfma(te, sp(pr.z), cz);
    }

    *(v2f*)&sred[0][part][2 * fp] = c00;
    *(v2f*)&sred[1][part][2 * fp] = cx;
    *(v2f*)&sred[2][part][2 * fp] = cy;
    *(v2f*)&sred[3][part][2 * fp] = cz;
    __syncthreads();

    for (int idx = tid; idx < 4 * C_; idx += 256) {
        const int k = idx >> 7, c = idx & 127;
        P[((size_t)(p * N_ + a) * 4) * C_ + idx] =
            sred[k][0][c] + sred[k][1][c] + sred[k][2][c] + sred[k][3][c];
    }
}

// ---------------------------------------------------------------------------
// Kernel C2: full-layer pair phase (RI = 2 or 7). grid = NSPLIT*N x 256 thr.
// x input f32 [N][4][C] component-major.
// ---------------------------------------------------------------------------
__global__ __launch_bounds__(256, 5) void pairF_kernel(
    const float* __restrict__ r, const float* __restrict__ xin,
    const uint2* __restrict__ tab, int RI, float* __restrict__ P)
{
    const int a = blockIdx.x / NSPLIT, p = blockIdx.x - a * NSPLIT;
    const int tid = threadIdx.x;
    const int fp = tid & 63, part = tid >> 6;
    const int bbase = p * NB_;

    __shared__ float4 pair[NB_];
    __shared__ int    qoff[NB_];
    __shared__ float  sred[11][4][C_];

    pair_setup(r, a, bbase, tid, RI, pair, qoff);
    __syncthreads();

    v2f a0 = sp(0.f), b1x = sp(0.f), b1y = sp(0.f), b1z = sp(0.f);
    v2f a1x = sp(0.f), a1y = sp(0.f), a1z = sp(0.f);
    v2f o0 = sp(0.f), o1x = sp(0.f), o1y = sp(0.f), o1z = sp(0.f);

    const uint2* tb = tab + fp;
    const float* xf = xin + ((size_t)bbase * 4) * C_ + 2 * fp;
    const int iBeg = part * (NB_ / 4), iEnd = iBeg + (NB_ / 4);
#pragma unroll 2
    for (int i = iBeg; i < iEnd; ++i) {
        const float4 pr = pair[i];
        const uint2* tp = tb + qoff[i];
        const uint2 w0 = tp[0 * FP_], w1 = tp[1 * FP_], w2 = tp[2 * FP_];
        const uint2 w3 = tp[3 * FP_], w4 = tp[4 * FP_];
        const float* xi = xf + (size_t)i * (4 * C_);
        const v2f x0b = *(const v2f*)&xi[0 * C_];
        const v2f xbx = *(const v2f*)&xi[1 * C_];
        const v2f xby = *(const v2f*)&xi[2 * C_];
        const v2f xbz = *(const v2f*)&xi[3 * C_];

        const __half2 fr2 = __float2half2_rn(pr.w);
        const v2f t0 = h2v(__hfma2(fr2, H2(w0.y), H2(w0.x)));
        const v2f t1 = h2v(__hfma2(fr2, H2(w1.y), H2(w1.x)));
        const v2f t2 = h2v(__hfma2(fr2, H2(w2.y), H2(w2.x)));
        const v2f t3 = h2v(__hfma2(fr2, H2(w3.y), H2(w3.x)));
        const v2f t4 = h2v(__hfma2(fr2, H2(w4.y), H2(w4.x)));

        const v2f ux = sp(pr.x), uy = sp(pr.y), uz = sp(pr.z);

        a0 = vfma(t0, x0b, a0);
        const v2f te = t1 * x0b;
        b1x = vfma(te, ux, b1x); b1y = vfma(te, uy, b1y); b1z = vfma(te, uz, b1z);
        a1x = vfma(t2, xbx, a1x); a1y = vfma(t2, xby, a1y); a1z = vfma(t2, xbz, a1z);
        v2f ud = xbx * ux; ud = vfma(xby, uy, ud); ud = vfma(xbz, uz, ud);
        o0 = vfma(t3, ud, o0);
        const v2f crx = xbz * uy - xby * uz;
        const v2f cry = xbx * uz - xbz * ux;
        const v2f crz = xby * ux - xbx * uy;
        o1x = vfma(t4, crx, o1x); o1y = vfma(t4, cry, o1y); o1z = vfma(t4, crz, o1z);
    }

    *(v2f*)&sred[0][part][2 * fp]  = a0;
    *(v2f*)&sred[1][part][2 * fp]  = b1x;
    *(v2f*)&sred[2][part][2 * fp]  = b1y;
    *(v2f*)&sred[3][part][2 * fp]  = b1z;
    *(v2f*)&sred[4][part][2 * fp]  = a1x;
    *(v2f*)&sred[5][part][2 * fp]  = a1y;
    *(v2f*)&sred[6][part][2 * fp]  = a1z;
    *(v2f*)&sred[7][part][2 * fp]  = o0;
    *(v2f*)&sred[8][part][2 * fp]  = o1x;
    *(v2f*)&sred[9][part][2 * fp]  = o1y;
    *(v2f*)&sred[10][part][2 * fp] = o1z;
    __syncthreads();

    for (int idx = tid; idx < 11 * C_; idx += 256) {
        const int k = idx >> 7, c = idx & 127;
        P[((size_t)(p * N_ + a) * 11) * C_ + idx] =
            sred[k][0][c] + sred[k][1][c] + sred[k][2][c] + sred[k][3][c];
    }
}

// ---------------------------------------------------------------------------
// Kernel D1: layer-0 finish. grid = N/TA x 512 thr; x out f32 [N][4][C].
// ---------------------------------------------------------------------------
__global__ __launch_bounds__(512) void finish0_kernel(
    const float* __restrict__ P,
    const float* __restrict__ w0, const float* __restrict__ b0v,
    const float* __restrict__ w1, const float* __restrict__ nlb,
    float* __restrict__ xout)
{
    const int a0_ = blockIdx.x * TA_, tid = threadIdx.x;
    const int f = tid & 127, j = tid >> 7;

    __shared__ float s[TA_][4 * C_];
    __shared__ float ys[TA_][4 * C_];

    for (int t = 0; t < TA_; ++t)
        for (int idx = tid; idx < 4 * C_; idx += 512) {
            float acc = 0.f;
            for (int sp_ = 0; sp_ < NSPLIT; ++sp_)
                acc += P[((size_t)(sp_ * N_ + a0_ + t) * 4) * C_ + idx];
            s[t][idx] = acc;
        }
    __syncthreads();

    float acc[TA_];
    if (j == 0) {
        const float b0 = b0v[f];
#pragma unroll
        for (int t = 0; t < TA_; ++t) acc[t] = b0;
        const float4* w = (const float4*)(w0 + (size_t)f * C_);
        for (int c4 = 0; c4 < C_ / 4; ++c4) {
            const float4 wv = w[c4];
#pragma unroll
            for (int t = 0; t < TA_; ++t) {
                const float4 sv = *(const float4*)&s[t][c4 * 4];
                acc[t] = fmaf(wv.x, sv.x, acc[t]);
                acc[t] = fmaf(wv.y, sv.y, acc[t]);
                acc[t] = fmaf(wv.z, sv.z, acc[t]);
                acc[t] = fmaf(wv.w, sv.w, acc[t]);
            }
        }
    } else {
#pragma unroll
        for (int t = 0; t < TA_; ++t) acc[t] = 0.f;
        const float4* w = (const float4*)(w1 + (size_t)f * C_);
        for (int c4 = 0; c4 < C_ / 4; ++c4) {
            const float4 wv = w[c4];
#pragma unroll
            for (int t = 0; t < TA_; ++t) {
                const float4 sv = *(const float4*)&s[t][j * C_ + c4 * 4];
                acc[t] = fmaf(wv.x, sv.x, acc[t]);
                acc[t] = fmaf(wv.y, sv.y, acc[t]);
                acc[t] = fmaf(wv.z, sv.z, acc[t]);
                acc[t] = fmaf(wv.w, sv.w, acc[t]);
            }
        }
    }
#pragma unroll
    for (int t = 0; t < TA_; ++t) ys[t][j * C_ + f] = acc[t];
    __syncthreads();

    if (tid < TA_ * C_) {
        const int t = tid >> 7, ff = tid & 127;
        const float y0 = ys[t][ff];
        const float yx = ys[t][C_ + ff], yy = ys[t][2 * C_ + ff], yz = ys[t][3 * C_ + ff];
        const float x0v = y0 > 0.f ? y0 : expm1f(y0);
        const float nsq = fmaf(yx, yx, fmaf(yy, yy, yz * yz));
        const float nn  = sqrtf(fmaxf(nsq, 1e-12f));
        const float g   = nlb[ff] + nn;
        const float sc  = (g > 0.f ? g : expm1f(g)) / nn;
        float* xo = xout + (size_t)(a0_ + t) * 4 * C_ + ff;
        xo[0 * C_] = x0v;
        xo[1 * C_] = yx * sc;
        xo[2 * C_] = yy * sc;
        xo[3 * C_] = yz * sc;
    }
}

// ---------------------------------------------------------------------------
// Kernel D2: full-layer finish. grid = N/TA x 512 thr.
// ---------------------------------------------------------------------------
template <bool NONLIN, bool LAST>
__global__ __launch_bounds__(512) void finishF_kernel(
    const float* __restrict__ P,
    const float* __restrict__ w0, const float* __restrict__ b0v,
    const float* __restrict__ w1, const float* __restrict__ nlb,
    float* __restrict__ xout,
    float* __restrict__ out, const float* __restrict__ predW,
    const float* __restrict__ predb)
{
    const int a0_ = blockIdx.x * TA_, tid = threadIdx.x;
    const int f = tid & 127, j = tid >> 7;

    __shared__ float s[TA_][11 * C_];
    __shared__ float ys[TA_][4 * C_];

    for (int t = 0; t < TA_; ++t)
        for (int idx = tid; idx < 11 * C_; idx += 512) {
            float acc = 0.f;
            for (int sp_ = 0; sp_ < NSPLIT; ++sp_)
                acc += P[((size_t)(sp_ * N_ + a0_ + t) * 11) * C_ + idx];
            s[t][idx] = acc;
        }
    __syncthreads();

    float acc[TA_];
    if (j == 0) {
        const float b0 = b0v[f];
#pragma unroll
        for (int t = 0; t < TA_; ++t) acc[t] = b0;
        const float4* w = (const float4*)(w0 + (size_t)f * (2 * C_));
        for (int c4 = 0; c4 < C_ / 4; ++c4) {
            const float4 wa = w[c4];
            const float4 wb = w[C_ / 4 + c4];
#pragma unroll
            for (int t = 0; t < TA_; ++t) {
                const float4 s0 = *(const float4*)&s[t][c4 * 4];
                const float4 s7 = *(const float4*)&s[t][7 * C_ + c4 * 4];
                acc[t] = fmaf(wa.x, s0.x, acc[t]);
                acc[t] = fmaf(wa.y, s0.y, acc[t]);
                acc[t] = fmaf(wa.z, s0.z, acc[t]);
                acc[t] = fmaf(wa.w, s0.w, acc[t]);
                acc[t] = fmaf(wb.x, s7.x, acc[t]);
                acc[t] = fmaf(wb.y, s7.y, acc[t]);
                acc[t] = fmaf(wb.z, s7.z, acc[t]);
                acc[t] = fmaf(wb.w, s7.w, acc[t]);
            }
        }
    } else {
#pragma unroll
        for (int t = 0; t < TA_; ++t) acc[t] = 0.f;
        const float4* w = (const float4*)(w1 + (size_t)f * (3 * C_));
        for (int c4 = 0; c4 < C_ / 4; ++c4) {
            const float4 wb = w[c4];
            const float4 wa = w[C_ / 4 + c4];
            const float4 wo = w[2 * (C_ / 4) + c4];
#pragma unroll
            for (int t = 0; t < TA_; ++t) {
                const float4 sb = *(const float4*)&s[t][j * C_ + c4 * 4];
                const float4 sa = *(const float4*)&s[t][(3 + j) * C_ + c4 * 4];
                const float4 so = *(const float4*)&s[t][(7 + j) * C_ + c4 * 4];
                acc[t] = fmaf(wb.x, sb.x, acc[t]);
                acc[t] = fmaf(wb.y, sb.y, acc[t]);
                acc[t] = fmaf(wb.z, sb.z, acc[t]);
                acc[t] = fmaf(wb.w, sb.w, acc[t]);
                acc[t] = fmaf(wa.x, sa.x, acc[t]);
                acc[t] = fmaf(wa.y, sa.y, acc[t]);
                acc[t] = fmaf(wa.z, sa.z, acc[t]);
                acc[t] = fmaf(wa.w, sa.w, acc[t]);
                acc[t] = fmaf(wo.x, so.x, acc[t]);
                acc[t] = fmaf(wo.y, so.y, acc[t]);
                acc[t] = fmaf(wo.z, so.z, acc[t]);
                acc[t] = fmaf(wo.w, so.w, acc[t]);
            }
        }
    }
#pragma unroll
    for (int t = 0; t < TA_; ++t) ys[t][j * C_ + f] = acc[t];
    __syncthreads();

    if (NONLIN) {
        if (tid < TA_ * C_) {
            const int t = tid >> 7, ff = tid & 127;
            const float y0 = ys[t][ff];
            const float yx = ys[t][C_ + ff], yy = ys[t][2 * C_ + ff], yz = ys[t][3 * C_ + ff];
            const float x0v = y0 > 0.f ? y0 : expm1f(y0);
            const float nsq = fmaf(yx, yx, fmaf(yy, yy, yz * yz));
            const float nn  = sqrtf(fmaxf(nsq, 1e-12f));
            const float g   = nlb[ff] + nn;
            const float sc  = (g > 0.f ? g : expm1f(g)) / nn;
            float* xo = xout + (size_t)(a0_ + t) * 4 * C_ + ff;
            xo[0 * C_] = x0v;
            xo[1 * C_] = yx * sc;
            xo[2 * C_] = yy * sc;
            xo[3 * C_] = yz * sc;
        }
    }
    if (LAST) {
        if (tid < TA_ * C_) {
            const int t = tid >> 7, ff = tid & 127;
            const int a = a0_ + t;
            const float y0 = ys[t][ff];
            const float yx = ys[t][C_ + ff], yy = ys[t][2 * C_ + ff], yz = ys[t][3 * C_ + ff];
            out[a * C_ + ff] = y0;                    // x0 [N,C,1]
            float* o1 = out + N_ * C_;                // x1 [N,C,3]
            o1[a * (C_ * 3) + ff * 3 + 0] = yx;
            o1[a * (C_ * 3) + ff * 3 + 1] = yy;
            o1[a * (C_ * 3) + ff * 3 + 2] = yz;
        }
        if (tid < TA_ * 8) {                          // atom head
            const int t = tid >> 3, o = tid & 7;
            float acc2 = predb[o];
            for (int c = 0; c < C_; ++c)
                acc2 = fmaf(predW[o * C_ + c], ys[t][c], acc2);
            out[N_ * C_ + N_ * C_ * 3 + (a0_ + t) * 8 + o] = acc2;
        }
    }
}

// ---------------------------------------------------------------------------
extern "C" void kernel_launch(void* const* d_in, const int* in_sizes, int n_in,
                              void* d_out, int out_size, void* d_ws, size_t ws_size,
                              hipStream_t stream)
{
    const float* r       = (const float*)d_in[0];
    const float* onehot  = (const float*)d_in[1];
    const float* embed_W = (const float*)d_in[2];
    const float* embed_b = (const float*)d_in[3];
    const float* Rw1     = (const float*)d_in[4];
    const float* Rb1     = (const float*)d_in[5];
    const float* Rw2     = (const float*)d_in[6];
    const float* Rb2     = (const float*)d_in[7];
    const float* si0_w0  = (const float*)d_in[8];
    const float* si0_b0  = (const float*)d_in[9];
    const float* si0_w1  = (const float*)d_in[10];
    const float* si1_w0  = (const float*)d_in[11];
    const float* si1_b0  = (const float*)d_in[12];
    const float* si1_w1  = (const float*)d_in[13];
    const float* si2_w0  = (const float*)d_in[14];
    const float* si2_b0  = (const float*)d_in[15];
    const float* si2_w1  = (const float*)d_in[16];
    const float* nl_b0   = (const float*)d_in[17];
    const float* nl_b1   = (const float*)d_in[18];
    const float* pred_W  = (const float*)d_in[19];
    const float* pred_b  = (const float*)d_in[20];
    (void)in_sizes; (void)n_in; (void)out_size; (void)ws_size;

    const float delta = DMAX_ / (float)(M_ - 1);

    // workspace (bytes): tab M*12*FP*8 = 3,145,728 | e 393,216 |
    // xa/xb N*4*C*4 = 1,572,864 each | P = NSPLIT*N*11*C*4 = 12,976,128
    // total ~19.7MB (>=24MB proven available in r8)
    char* wsb = (char*)d_ws;
    size_t off = 0;
    uint2* table = (uint2*)(wsb + off); off += (size_t)M_ * 12 * FP_ * 8;
    float* e     = (float*)(wsb + off); off += (size_t)N_ * C_ * 4;
    float* xa    = (float*)(wsb + off); off += (size_t)N_ * 4 * C_ * 4;
    float* xb    = (float*)(wsb + off); off += (size_t)N_ * 4 * C_ * 4;
    float* P     = (float*)(wsb + off);

    float* out = (float*)d_out;

    build_table_kernel<<<M_ / 4, 256, 0, stream>>>(Rw1, Rb1, Rw2, Rb2, table, delta);
    embed_kernel<<<(N_ * C_) / 256, 256, 0, stream>>>(onehot, embed_W, embed_b, e);

    // layer 0
    pair0_kernel<<<NSPLIT * N_, 256, 0, stream>>>(r, e, table, P);
    finish0_kernel<<<N_ / TA_, 512, 0, stream>>>(P, si0_w0, si0_b0, si0_w1,
                                                 nl_b0, xa);
    // layer 1
    pairF_kernel<<<NSPLIT * N_, 256, 0, stream>>>(r, xa, table, 2, P);
    finishF_kernel<true, false><<<N_ / TA_, 512, 0, stream>>>(
        P, si1_w0, si1_b0, si1_w1, nl_b1, xb, nullptr, nullptr, nullptr);

    // layer 2 (last)
    pairF_kernel<<<NSPLIT * N_, 256, 0, stream>>>(r, xb, table, 7, P);
    finishF_kernel<false, true><<<N_ / TA_, 512, 0, stream>>>(
        P, si2_w0, si2_b0, si2_w1, nullptr, nullptr, out, pred_W, pred_b);
}

// Round 12
// 452.415 us; speedup vs baseline: 1.2308x; 1.2308x over previous
//
#include <hip/hip_runtime.h>
#include <hip/hip_fp16.h>
#include <math.h>

// ---------------------------------------------------------------------------
// TensorFieldNetwork on MI355X — round 11 design (2nd submit; round 11 bench
// never ran: GPU acquisition timeout).
// Round-10 post-mortem: v2f dual-fp32 REGRESSED (pairF 123->163us, VALUBusy
// 76->28%) — it traded VALU for 9 VMEM/iter and went latency-bound. Reverting
// to round-9 structure (best: 497us). Evidence r6/r8/r9/r10: pairF sits at a
// mixed VALU/L2 equilibrium (~17 TB/s L2, ~50% of aggregate) invariant to
// occupancy and instruction-mix tweaks.
// This round: fix the REMAINDER. build_table ran 128 blocks on 256 CUs (half
// idle) -> split filters across blocks: grid (M/4 x 6) = 768 blocks. Add
// unroll 4 to pair loops. Everything else identical to round 9.
// ---------------------------------------------------------------------------

constexpr int   N_     = 768;
constexpr int   C_     = 128;
constexpr int   M_     = 512;
constexpr int   NSPLIT = 3;
constexpr int   NB_    = N_ / NSPLIT;   // 256 neighbors per pair-block
constexpr int   TA_    = 3;             // atoms per finish block
constexpr float DMAX_  = 6.4f;
constexpr float GAMMA_ = 1.6f;          // RBF / (HIGH - LOW)

// lerp from packed {v, d} half2: t = v + fr * d   (v_fma_mix candidate)
__device__ inline float lerp_vd(float fr, __half2 vd) {
    return fmaf(fr, __half2float(__high2half(vd)), __half2float(__low2half(vd)));
}

// ---------------------------------------------------------------------------
// Kernel A: build radial tables, fp16 {val, delta}, layout tab[(m*12+i)*C+f].
// grid = (M/4) x 6 blocks, 256 thr. Block (mg, fg): m = mg*4..+3,
// filter i = fg*2 + (tid>>7). 768 blocks -> 3 blocks/CU (was 128 -> 0.5/CU).
// ---------------------------------------------------------------------------
__global__ __launch_bounds__(256) void build_table_kernel(
    const float* __restrict__ Rw1, const float* __restrict__ Rb1,
    const float* __restrict__ Rw2, const float* __restrict__ Rb2,
    __half2* __restrict__ tab, float delta)
{
    const int f  = threadIdx.x & 127, fh = threadIdx.x >> 7;
    const int mg = blockIdx.x / 6, fg = blockIdx.x - mg * 6;
    const int m0 = mg * 4;
    const int i  = fg * 2 + fh;

    __shared__ float hs[2][5][C_];

    float rbf[5][4];
    const float cent[4] = {0.0f, 2.5f / 3.0f, 5.0f / 3.0f, 2.5f};
#pragma unroll
    for (int mm = 0; mm < 5; ++mm) {
        int m = m0 + mm; if (m > M_ - 1) m = M_ - 1;
        const float d = (float)m * delta;
#pragma unroll
        for (int k = 0; k < 4; ++k) {
            const float t = d - cent[k];
            rbf[mm][k] = expf(-GAMMA_ * t * t);
        }
    }

    float w1v[4];
#pragma unroll
    for (int k = 0; k < 4; ++k) w1v[k] = Rw1[(i * 4 + k) * C_ + f];
    const float b1v = Rb1[i * C_ + f];

#pragma unroll
    for (int mm = 0; mm < 5; ++mm) {
        float acc = b1v;
#pragma unroll
        for (int k = 0; k < 4; ++k) acc = fmaf(rbf[mm][k], w1v[k], acc);
        hs[fh][mm][f] = fmaxf(acc, 0.0f);
    }
    __syncthreads();

    const float b2v = Rb2[i * C_ + f];
    float out[5] = {b2v, b2v, b2v, b2v, b2v};
    for (int c = 0; c < C_; ++c) {
        const float w = Rw2[((size_t)i * C_ + c) * C_ + f];
#pragma unroll
        for (int mm = 0; mm < 5; ++mm) out[mm] = fmaf(hs[fh][mm][c], w, out[mm]);
    }
#pragma unroll
    for (int mm = 0; mm < 4; ++mm) {
        const int m = m0 + mm;
        if (m < M_)
            tab[((size_t)m * 12 + i) * C_ + f] =
                __floats2half2_rn(out[mm], out[mm + 1] - out[mm]);
    }
}

// ---------------------------------------------------------------------------
// Kernel B: embedding
// ---------------------------------------------------------------------------
__global__ __launch_bounds__(256) void embed_kernel(
    const float* __restrict__ onehot, const float* __restrict__ eW,
    const float* __restrict__ eb, float* __restrict__ e)
{
    const int idx = blockIdx.x * 256 + threadIdx.x;
    const int b = idx >> 7, f = idx & 127;
    float acc = eb[f];
#pragma unroll
    for (int t = 0; t < 8; ++t) acc = fmaf(onehot[b * 8 + t], eW[f * 8 + t], acc);
    e[idx] = acc;
}

// ---------------------------------------------------------------------------
// Pair setup: {u, fr} + table element offset (q*12+RI)*C for NB_ neighbors.
// ---------------------------------------------------------------------------
__device__ inline void pair_setup(const float* __restrict__ r, int a, int bbase,
                                  int tid, int RI, float4* pair, int* qoff)
{
    const float rax = r[a * 3 + 0], ray = r[a * 3 + 1], raz = r[a * 3 + 2];
    for (int i = tid; i < NB_; i += 256) {
        const int b = bbase + i;
        const float dx = rax - r[b * 3 + 0];
        const float dy = ray - r[b * 3 + 1];
        const float dz = raz - r[b * 3 + 2];
        const float d2 = fmaf(dx, dx, fmaf(dy, dy, dz * dz));
        const float d  = sqrtf(fmaxf(d2, 1e-12f));
        const float inv = 1.0f / (d + 1e-8f);
        const float t = d * ((float)(M_ - 1) / DMAX_);
        int q = (int)t; q = q > M_ - 2 ? M_ - 2 : q;
        const float fr = fminf(t - (float)q, 1.0f);
        pair[i] = make_float4(dx * inv, dy * inv, dz * inv, fr);
        qoff[i] = (q * 12 + RI) * C_;
    }
}

// ---------------------------------------------------------------------------
// Kernel C1: layer-0 pair phase. grid = NSPLIT*N x 256 thr.
// ---------------------------------------------------------------------------
__global__ __launch_bounds__(256, 8) void pair0_kernel(
    const float* __restrict__ r, const float* __restrict__ e,
    const __half2* __restrict__ tab, float* __restrict__ P)
{
    const int a = blockIdx.x / NSPLIT, p = blockIdx.x - a * NSPLIT;
    const int tid = threadIdx.x;
    const int f = tid & 127, part = tid >> 7;
    const int bbase = p * NB_;

    __shared__ float4 pair[NB_];
    __shared__ int    qoff[NB_];
    __shared__ float  sred[4][2][C_];

    pair_setup(r, a, bbase, tid, 0, pair, qoff);
    __syncthreads();

    float c00 = 0.f, cx = 0.f, cy = 0.f, cz = 0.f;
    const __half2* tabf = tab + f;
    const float*   ef   = e + (size_t)bbase * C_ + f;
    const int iBeg = part * (NB_ / 2), iEnd = iBeg + (NB_ / 2);
#pragma unroll 4
    for (int i = iBeg; i < iEnd; ++i) {
        const float4 pr = pair[i];
        const __half2* tp = tabf + qoff[i];
        const __half2 h0 = tp[0], h1 = tp[C_];
        const float eb_ = ef[(size_t)i * C_];
        const float fr = pr.w;
        const float t0 = lerp_vd(fr, h0);
        const float t1 = lerp_vd(fr, h1);
        c00 = fmaf(t0, eb_, c00);
        const float te = t1 * eb_;
        cx = fmaf(te, pr.x, cx); cy = fmaf(te, pr.y, cy); cz = fmaf(te, pr.z, cz);
    }

    sred[0][part][f] = c00;
    sred[1][part][f] = cx;
    sred[2][part][f] = cy;
    sred[3][part][f] = cz;
    __syncthreads();

    for (int idx = tid; idx < 4 * C_; idx += 256) {
        const int k = idx >> 7, c = idx & 127;
        P[((size_t)(p * N_ + a) * 4) * C_ + idx] = sred[k][0][c] + sred[k][1][c];
    }
}

// ---------------------------------------------------------------------------
// Kernel C2: full-layer pair phase (RI = 2 or 7). grid = NSPLIT*N x 256 thr.
// ---------------------------------------------------------------------------
__global__ __launch_bounds__(256, 8) void pairF_kernel(
    const float* __restrict__ r, const uint2* __restrict__ xin,
    const __half2* __restrict__ tab, int RI, float* __restrict__ P)
{
    const int a = blockIdx.x / NSPLIT, p = blockIdx.x - a * NSPLIT;
    const int tid = threadIdx.x;
    const int f = tid & 127, part = tid >> 7;
    const int bbase = p * NB_;

    __shared__ float4 pair[NB_];
    __shared__ int    qoff[NB_];
    __shared__ float  sred[11][2][C_];

    pair_setup(r, a, bbase, tid, RI, pair, qoff);
    __syncthreads();

    float a0 = 0.f, b1x = 0.f, b1y = 0.f, b1z = 0.f;
    float a1x = 0.f, a1y = 0.f, a1z = 0.f;
    float o0 = 0.f, o1x = 0.f, o1y = 0.f, o1z = 0.f;

    const __half2* tabf = tab + f;
    const uint2*   xf   = xin + (size_t)bbase * C_ + f;
    const int iBeg = part * (NB_ / 2), iEnd = iBeg + (NB_ / 2);
#pragma unroll 4
    for (int i = iBeg; i < iEnd; ++i) {
        const float4 pr = pair[i];
        const __half2* tp = tabf + qoff[i];
        const __half2 h0 = tp[0 * C_], h1 = tp[1 * C_], h2 = tp[2 * C_];
        const __half2 h3 = tp[3 * C_], h4 = tp[4 * C_];
        const uint2 xw = xf[(size_t)i * C_];

        const float fr = pr.w;
        const float t0 = lerp_vd(fr, h0);
        const float t1 = lerp_vd(fr, h1);
        const float t2 = lerp_vd(fr, h2);
        const float t3 = lerp_vd(fr, h3);
        const float t4 = lerp_vd(fr, h4);

        const __half2 xh01 = *(const __half2*)&xw.x;
        const __half2 xh23 = *(const __half2*)&xw.y;
        const float x0b = __half2float(__low2half(xh01));
        const float xbx = __half2float(__high2half(xh01));
        const float xby = __half2float(__low2half(xh23));
        const float xbz = __half2float(__high2half(xh23));

        a0 = fmaf(t0, x0b, a0);
        const float tb = t1 * x0b;
        b1x = fmaf(tb, pr.x, b1x); b1y = fmaf(tb, pr.y, b1y); b1z = fmaf(tb, pr.z, b1z);
        a1x = fmaf(t2, xbx, a1x); a1y = fmaf(t2, xby, a1y); a1z = fmaf(t2, xbz, a1z);
        const float ud = fmaf(pr.x, xbx, fmaf(pr.y, xby, pr.z * xbz));
        o0 = fmaf(t3, ud, o0);
        const float crx = pr.y * xbz - pr.z * xby;
        const float cry = pr.z * xbx - pr.x * xbz;
        const float crz = pr.x * xby - pr.y * xbx;
        o1x = fmaf(t4, crx, o1x); o1y = fmaf(t4, cry, o1y); o1z = fmaf(t4, crz, o1z);
    }

    sred[0][part][f] = a0;
    sred[1][part][f] = b1x; sred[2][part][f] = b1y; sred[3][part][f] = b1z;
    sred[4][part][f] = a1x; sred[5][part][f] = a1y; sred[6][part][f] = a1z;
    sred[7][part][f] = o0;
    sred[8][part][f] = o1x; sred[9][part][f] = o1y; sred[10][part][f] = o1z;
    __syncthreads();

    for (int idx = tid; idx < 11 * C_; idx += 256) {
        const int k = idx >> 7, c = idx & 127;
        P[((size_t)(p * N_ + a) * 11) * C_ + idx] = sred[k][0][c] + sred[k][1][c];
    }
}

// ---------------------------------------------------------------------------
// Kernel D1: layer-0 finish. grid = N/TA x 512 thr; TA atoms per block.
// ---------------------------------------------------------------------------
__global__ __launch_bounds__(512) void finish0_kernel(
    const float* __restrict__ P,
    const float* __restrict__ w0, const float* __restrict__ b0v,
    const float* __restrict__ w1, const float* __restrict__ nlb,
    uint2* __restrict__ xout)
{
    const int a0_ = blockIdx.x * TA_, tid = threadIdx.x;
    const int f = tid & 127, j = tid >> 7;

    __shared__ float s[TA_][4 * C_];
    __shared__ float ys[TA_][4 * C_];

    for (int t = 0; t < TA_; ++t)
        for (int idx = tid; idx < 4 * C_; idx += 512) {
            float acc = 0.f;
            for (int sp = 0; sp < NSPLIT; ++sp)
                acc += P[((size_t)(sp * N_ + a0_ + t) * 4) * C_ + idx];
            s[t][idx] = acc;
        }
    __syncthreads();

    float acc[TA_];
    if (j == 0) {
        const float b0 = b0v[f];
#pragma unroll
        for (int t = 0; t < TA_; ++t) acc[t] = b0;
        const float4* w = (const float4*)(w0 + (size_t)f * C_);
        for (int c4 = 0; c4 < C_ / 4; ++c4) {
            const float4 wv = w[c4];
#pragma unroll
            for (int t = 0; t < TA_; ++t) {
                const float4 sv = *(const float4*)&s[t][c4 * 4];
                acc[t] = fmaf(wv.x, sv.x, acc[t]);
                acc[t] = fmaf(wv.y, sv.y, acc[t]);
                acc[t] = fmaf(wv.z, sv.z, acc[t]);
                acc[t] = fmaf(wv.w, sv.w, acc[t]);
            }
        }
    } else {
#pragma unroll
        for (int t = 0; t < TA_; ++t) acc[t] = 0.f;
        const float4* w = (const float4*)(w1 + (size_t)f * C_);
        for (int c4 = 0; c4 < C_ / 4; ++c4) {
            const float4 wv = w[c4];
#pragma unroll
            for (int t = 0; t < TA_; ++t) {
                const float4 sv = *(const float4*)&s[t][j * C_ + c4 * 4];
                acc[t] = fmaf(wv.x, sv.x, acc[t]);
                acc[t] = fmaf(wv.y, sv.y, acc[t]);
                acc[t] = fmaf(wv.z, sv.z, acc[t]);
                acc[t] = fmaf(wv.w, sv.w, acc[t]);
            }
        }
    }
#pragma unroll
    for (int t = 0; t < TA_; ++t) ys[t][j * C_ + f] = acc[t];
    __syncthreads();

    if (tid < TA_ * C_) {
        const int t = tid >> 7, ff = tid & 127;
        const float y0 = ys[t][ff];
        const float yx = ys[t][C_ + ff], yy = ys[t][2 * C_ + ff], yz = ys[t][3 * C_ + ff];
        const float x0v = y0 > 0.f ? y0 : expm1f(y0);
        const float nsq = fmaf(yx, yx, fmaf(yy, yy, yz * yz));
        const float nn  = sqrtf(fmaxf(nsq, 1e-12f));
        const float g   = nlb[ff] + nn;
        const float sc  = (g > 0.f ? g : expm1f(g)) / nn;
        uint2 w;
        *(__half2*)&w.x = __floats2half2_rn(x0v, yx * sc);
        *(__half2*)&w.y = __floats2half2_rn(yy * sc, yz * sc);
        xout[(size_t)(a0_ + t) * C_ + ff] = w;
    }
}

// ---------------------------------------------------------------------------
// Kernel D2: full-layer finish. grid = N/TA x 512 thr.
// ---------------------------------------------------------------------------
template <bool NONLIN, bool LAST>
__global__ __launch_bounds__(512) void finishF_kernel(
    const float* __restrict__ P,
    const float* __restrict__ w0, const float* __restrict__ b0v,
    const float* __restrict__ w1, const float* __restrict__ nlb,
    uint2* __restrict__ xout,
    float* __restrict__ out, const float* __restrict__ predW,
    const float* __restrict__ predb)
{
    const int a0_ = blockIdx.x * TA_, tid = threadIdx.x;
    const int f = tid & 127, j = tid >> 7;

    __shared__ float s[TA_][11 * C_];
    __shared__ float ys[TA_][4 * C_];

    for (int t = 0; t < TA_; ++t)
        for (int idx = tid; idx < 11 * C_; idx += 512) {
            float acc = 0.f;
            for (int sp = 0; sp < NSPLIT; ++sp)
                acc += P[((size_t)(sp * N_ + a0_ + t) * 11) * C_ + idx];
            s[t][idx] = acc;
        }
    __syncthreads();

    float acc[TA_];
    if (j == 0) {
        const float b0 = b0v[f];
#pragma unroll
        for (int t = 0; t < TA_; ++t) acc[t] = b0;
        const float4* w = (const float4*)(w0 + (size_t)f * (2 * C_));
        for (int c4 = 0; c4 < C_ / 4; ++c4) {
            const float4 wa = w[c4];
            const float4 wb = w[C_ / 4 + c4];
#pragma unroll
            for (int t = 0; t < TA_; ++t) {
                const float4 s0 = *(const float4*)&s[t][c4 * 4];
                const float4 s7 = *(const float4*)&s[t][7 * C_ + c4 * 4];
                acc[t] = fmaf(wa.x, s0.x, acc[t]);
                acc[t] = fmaf(wa.y, s0.y, acc[t]);
                acc[t] = fmaf(wa.z, s0.z, acc[t]);
                acc[t] = fmaf(wa.w, s0.w, acc[t]);
                acc[t] = fmaf(wb.x, s7.x, acc[t]);
                acc[t] = fmaf(wb.y, s7.y, acc[t]);
                acc[t] = fmaf(wb.z, s7.z, acc[t]);
                acc[t] = fmaf(wb.w, s7.w, acc[t]);
            }
        }
    } else {
#pragma unroll
        for (int t = 0; t < TA_; ++t) acc[t] = 0.f;
        const float4* w = (const float4*)(w1 + (size_t)f * (3 * C_));
        for (int c4 = 0; c4 < C_ / 4; ++c4) {
            const float4 wb = w[c4];
            const float4 wa = w[C_ / 4 + c4];
            const float4 wo = w[2 * (C_ / 4) + c4];
#pragma unroll
            for (int t = 0; t < TA_; ++t) {
                const float4 sb = *(const float4*)&s[t][j * C_ + c4 * 4];
                const float4 sa = *(const float4*)&s[t][(3 + j) * C_ + c4 * 4];
                const float4 so = *(const float4*)&s[t][(7 + j) * C_ + c4 * 4];
                acc[t] = fmaf(wb.x, sb.x, acc[t]);
                acc[t] = fmaf(wb.y, sb.y, acc[t]);
                acc[t] = fmaf(wb.z, sb.z, acc[t]);
                acc[t] = fmaf(wb.w, sb.w, acc[t]);
                acc[t] = fmaf(wa.x, sa.x, acc[t]);
                acc[t] = fmaf(wa.y, sa.y, acc[t]);
                acc[t] = fmaf(wa.z, sa.z, acc[t]);
                acc[t] = fmaf(wa.w, sa.w, acc[t]);
                acc[t] = fmaf(wo.x, so.x, acc[t]);
                acc[t] = fmaf(wo.y, so.y, acc[t]);
                acc[t] = fmaf(wo.z, so.z, acc[t]);
                acc[t] = fmaf(wo.w, so.w, acc[t]);
            }
        }
    }
#pragma unroll
    for (int t = 0; t < TA_; ++t) ys[t][j * C_ + f] = acc[t];
    __syncthreads();

    if (NONLIN) {
        if (tid < TA_ * C_) {
            const int t = tid >> 7, ff = tid & 127;
            const float y0 = ys[t][ff];
            const float yx = ys[t][C_ + ff], yy = ys[t][2 * C_ + ff], yz = ys[t][3 * C_ + ff];
            const float x0v = y0 > 0.f ? y0 : expm1f(y0);
            const float nsq = fmaf(yx, yx, fmaf(yy, yy, yz * yz));
            const float nn  = sqrtf(fmaxf(nsq, 1e-12f));
            const float g   = nlb[ff] + nn;
            const float sc  = (g > 0.f ? g : expm1f(g)) / nn;
            uint2 w;
            *(__half2*)&w.x = __floats2half2_rn(x0v, yx * sc);
            *(__half2*)&w.y = __floats2half2_rn(yy * sc, yz * sc);
            xout[(size_t)(a0_ + t) * C_ + ff] = w;
        }
    }
    if (LAST) {
        if (tid < TA_ * C_) {
            const int t = tid >> 7, ff = tid & 127;
            const int a = a0_ + t;
            const float y0 = ys[t][ff];
            const float yx = ys[t][C_ + ff], yy = ys[t][2 * C_ + ff], yz = ys[t][3 * C_ + ff];
            out[a * C_ + ff] = y0;                    // x0 [N,C,1]
            float* o1 = out + N_ * C_;                // x1 [N,C,3]
            o1[a * (C_ * 3) + ff * 3 + 0] = yx;
            o1[a * (C_ * 3) + ff * 3 + 1] = yy;
            o1[a * (C_ * 3) + ff * 3 + 2] = yz;
        }
        if (tid < TA_ * 8) {                          // atom head
            const int t = tid >> 3, o = tid & 7;
            float acc2 = predb[o];
            for (int c = 0; c < C_; ++c)
                acc2 = fmaf(predW[o * C_ + c], ys[t][c], acc2);
            out[N_ * C_ + N_ * C_ * 3 + (a0_ + t) * 8 + o] = acc2;
        }
    }
}

// ---------------------------------------------------------------------------
extern "C" void kernel_launch(void* const* d_in, const int* in_sizes, int n_in,
                              void* d_out, int out_size, void* d_ws, size_t ws_size,
                              hipStream_t stream)
{
    const float* r       = (const float*)d_in[0];
    const float* onehot  = (const float*)d_in[1];
    const float* embed_W = (const float*)d_in[2];
    const float* embed_b = (const float*)d_in[3];
    const float* Rw1     = (const float*)d_in[4];
    const float* Rb1     = (const float*)d_in[5];
    const float* Rw2     = (const float*)d_in[6];
    const float* Rb2     = (const float*)d_in[7];
    const float* si0_w0  = (const float*)d_in[8];
    const float* si0_b0  = (const float*)d_in[9];
    const float* si0_w1  = (const float*)d_in[10];
    const float* si1_w0  = (const float*)d_in[11];
    const float* si1_b0  = (const float*)d_in[12];
    const float* si1_w1  = (const float*)d_in[13];
    const float* si2_w0  = (const float*)d_in[14];
    const float* si2_b0  = (const float*)d_in[15];
    const float* si2_w1  = (const float*)d_in[16];
    const float* nl_b0   = (const float*)d_in[17];
    const float* nl_b1   = (const float*)d_in[18];
    const float* pred_W  = (const float*)d_in[19];
    const float* pred_b  = (const float*)d_in[20];
    (void)in_sizes; (void)n_in; (void)out_size; (void)ws_size;

    const float delta = DMAX_ / (float)(M_ - 1);

    // workspace (bytes): tab 3,145,728 | e 393,216 | xa/xb 786,432 each |
    // P = NSPLIT*N*11*C*4 = 12,976,128   -> total ~18.1MB
    char* wsb = (char*)d_ws;
    size_t off = 0;
    __half2* table = (__half2*)(wsb + off); off += (size_t)M_ * 12 * C_ * 4;
    float*   e     = (float*)(wsb + off);   off += (size_t)N_ * C_ * 4;
    uint2*   xa    = (uint2*)(wsb + off);   off += (size_t)N_ * C_ * 8;
    uint2*   xb    = (uint2*)(wsb + off);   off += (size_t)N_ * C_ * 8;
    float*   P     = (float*)(wsb + off);

    float* out = (float*)d_out;

    build_table_kernel<<<(M_ / 4) * 6, 256, 0, stream>>>(Rw1, Rb1, Rw2, Rb2,
                                                         table, delta);
    embed_kernel<<<(N_ * C_) / 256, 256, 0, stream>>>(onehot, embed_W, embed_b, e);

    // layer 0
    pair0_kernel<<<NSPLIT * N_, 256, 0, stream>>>(r, e, table, P);
    finish0_kernel<<<N_ / TA_, 512, 0, stream>>>(P, si0_w0, si0_b0, si0_w1,
                                                 nl_b0, xa);
    // layer 1
    pairF_kernel<<<NSPLIT * N_, 256, 0, stream>>>(r, xa, table, 2, P);
    finishF_kernel<true, false><<<N_ / TA_, 512, 0, stream>>>(
        P, si1_w0, si1_b0, si1_w1, nl_b1, xb, nullptr, nullptr, nullptr);

    // layer 2 (last)
    pairF_kernel<<<NSPLIT * N_, 256, 0, stream>>>(r, xb, table, 7, P);
    finishF_kernel<false, true><<<N_ / TA_, 512, 0, stream>>>(
        P, si2_w0, si2_b0, si2_w1, nullptr, nullptr, out, pred_W, pred_b);
}